// Round 16
// baseline (298.192 us; speedup 1.0000x reference)
//
#include <hip/hip_runtime.h>
#include <math.h>

#define B 16
#define T 6000
#define H 256
#define NPOS 6001            // T+1 segments
#define NOTE_CLS 104
#define NOTE_NUM 100
#define NOTE_START 30
#define MIN_GAP 9
#define SEGC 384             // materialized agg/u rows per batch (len ~255 + headroom)

#define T2 16                // k_tail tile (positions)
#define NT2 ((NPOS + T2 - 1) / T2)      // 376
#define CT 4                 // conv tile (positions per block)
#define NCT (SEGC / CT)      // 96
#define ZSTR 260

#define NWORDS 94            // ceil(T/64)
#define MAXRUNS 3088

// ---------------- Kernel 1: bd + attn dot products (f64 accumulate) ----------
__global__ __launch_bounds__(256) void k_dots(
    const float* __restrict__ feat,
    const float* __restrict__ w_bd, const float* __restrict__ b_bd,
    const float* __restrict__ w_attn, const float* __restrict__ b_attn,
    float* __restrict__ out_logits, double* __restrict__ dlog,
    float* __restrict__ amean)
{
  int lane = threadIdx.x & 63, wv = threadIdx.x >> 6;
  int row = blockIdx.x * 4 + wv;                      // b*T + t
  if (row >= B * T) return;
  float4 f  = ((const float4*)(feat + (size_t)row * H))[lane];
  float4 wb = ((const float4*)w_bd)[lane];
  float4 wa = ((const float4*)w_attn)[lane];
  double sb = (double)f.x * wb.x + (double)f.y * wb.y + (double)f.z * wb.z + (double)f.w * wb.w;
  double sa = (double)f.x * wa.x + (double)f.y * wa.y + (double)f.z * wa.z + (double)f.w * wa.w;
  for (int off = 32; off; off >>= 1) { sb += __shfl_down(sb, off); sa += __shfl_down(sa, off); }
  if (lane == 0) {
    double lb = sb + (double)b_bd[0];
    lb = fmin(fmax(lb, -16.0), 16.0);
    out_logits[row] = (float)lb;
    dlog[row] = lb;
    double la = sa + (double)b_attn[0];
    amean[row] = (float)(1.0 / (1.0 + exp(-la)));
  }
}

// ---------------- block-wide exclusive scan helper (in-place), n uniform -----
__device__ __forceinline__ int block_scan_excl(int* a, int n, int tid, int lane,
                                               int wv, int* wsums)
{
  int base = 0;
  for (int c0 = 0; c0 < n; c0 += 256) {
    int i = c0 + tid;
    int v = (i < n) ? a[i] : 0;
    int s = v;
    #pragma unroll
    for (int off = 1; off < 64; off <<= 1) {
      int t = __shfl_up(s, off);
      if (lane >= off) s += t;
    }
    if (lane == 63) wsums[wv] = s;
    __syncthreads();
    int wbase = 0;
    for (int w = 0; w < wv; ++w) wbase += wsums[w];
    int ctot = wsums[0] + wsums[1] + wsums[2] + wsums[3];
    if (i < n) a[i] = base + wbase + s - v;    // exclusive
    base += ctot;
    __syncthreads();
  }
  return base;
}

// ---------------- Kernel 2: regulate_boundary (cluster-parallel chain) -------
__global__ __launch_bounds__(256) void k_regulate(
    const double* __restrict__ dlog, const int* __restrict__ non_padding,
    float* __restrict__ out_bd, float* __restrict__ out_len,
    int* __restrict__ seg_start, int* __restrict__ note_len)
{
  __shared__ double row_s[T];                    // 48000 B
  __shared__ unsigned long long words[96];
  __shared__ unsigned long long smask[NWORDS], emask[NWORDS];
  __shared__ int wcnt[NWORDS], woff[NWORDS], ecnt[NWORDS], eoff[NWORDS];
  __shared__ int starts_s[MAXRUNS];
  __shared__ int ends_s[MAXRUNS];
  __shared__ int besti_s[MAXRUNS];
  __shared__ int cstart_s[MAXRUNS + 1];
  __shared__ int kofs_s[MAXRUNS];
  __shared__ unsigned long long cmask[52];
  __shared__ int ccnt[52], coff[52];
  __shared__ int wsums[4], red_i[4];
  __shared__ int R_s, NC_s, lens_s;

  int b = blockIdx.x, tid = threadIdx.x;
  int lane = tid & 63, wv = tid >> 6;
  const double* row = dlog + (size_t)b * T;

  // --- Phase A: stage row in LDS + bit words ---
  for (int c = 0; c < 24; ++c) {
    int t = c * 256 + tid;
    double d = (t < T) ? row[t] : -1.0;
    if (t < T) row_s[t] = d;
    unsigned long long m = __ballot((t < T) && (d > 0.0));
    if (lane == 0) words[c * 4 + wv] = m;
  }
  __syncthreads();

  if (tid < NWORDS) {
    unsigned long long bits = words[tid];
    unsigned long long carry = (tid > 0) ? (words[tid - 1] >> 63) : 0ull;
    unsigned long long pm = (bits << 1) | carry;
    unsigned long long sm = bits & ~pm;
    unsigned long long em = (~bits) & pm;
    smask[tid] = sm;  emask[tid] = em;
    wcnt[tid] = __popcll(sm);  ecnt[tid] = __popcll(em);
  }
  __syncthreads();

  if (tid == 0) {
    int a = 0, e = 0;
    #pragma unroll 8
    for (int w = 0; w < NWORDS; ++w) {
      woff[w] = a; a += wcnt[w];
      eoff[w] = e; e += ecnt[w];
    }
    R_s = a;
  }
  __syncthreads();

  if (tid < NWORDS) {
    unsigned long long m = smask[tid];
    int off = woff[tid], base = tid * 64;
    while (m) { int i = __builtin_ctzll(m); starts_s[off++] = base + i; m &= m - 1; }
    m = emask[tid]; off = eoff[tid];
    while (m) { int i = __builtin_ctzll(m); ends_s[off++] = base + i; m &= m - 1; }
  }

  {
    int lens = 0;
    const int* npr = non_padding + (size_t)b * T;
    for (int t = tid; t < T; t += 256) lens += npr[t];
    for (int off = 32; off; off >>= 1) lens += __shfl_down(lens, off);
    if (lane == 0) red_i[wv] = lens;
  }
  __syncthreads();
  if (tid == 0) lens_s = red_i[0] + red_i[1] + red_i[2] + red_i[3];

  int R = R_s;
  int bd_last = (int)((words[(T - 1) >> 6] >> ((T - 1) & 63)) & 1ull);
  int Rc = R - (bd_last ? 1 : 0);          // trailing unclosed run excluded

  // --- Phase B: per-run argmax (break-free, LDS reads) ---
  for (int r = tid; r < R; r += 256) {
    int s = starts_s[r];
    int e = (r < Rc) ? ends_s[r] : T;
    double bv = row_s[s];
    int bi = s;
    for (int t = s + 1; t < e; ++t) {
      double d = row_s[t];
      if (d > bv) { bv = d; bi = t; }
    }
    besti_s[r] = bi;
  }
  __syncthreads();

  // --- cluster boundaries ---
  int NRW = (Rc + 63) >> 6;
  for (int c0 = 0; c0 < NRW * 64; c0 += 256) {
    int r = c0 + tid;
    bool fl = false;
    if (r < Rc) fl = (r == 0) || (besti_s[r] - besti_s[r - 1] >= MIN_GAP);
    unsigned long long m = __ballot(fl);
    int widx = (c0 >> 6) + wv;
    if (lane == 0 && widx < 52) cmask[widx] = m;
  }
  __syncthreads();
  if (tid < NRW) ccnt[tid] = __popcll(cmask[tid]);
  __syncthreads();
  if (tid == 0) {
    int a = 0;
    for (int w = 0; w < NRW; ++w) { coff[w] = a; a += ccnt[w]; }
    NC_s = a;
  }
  __syncthreads();
  if (tid < NRW) {
    unsigned long long m = cmask[tid];
    int off = coff[tid], base = tid * 64;
    while (m) { int i = __builtin_ctzll(m); cstart_s[off++] = base + i; m &= m - 1; }
  }
  __syncthreads();
  int NC = NC_s;
  if (tid == 0) cstart_s[NC] = Rc;
  __syncthreads();

  // --- Phase C: per-cluster merge chains ---
  for (int j = tid; j < NC; j += 256) {
    int r0 = cstart_s[j], r1 = cstart_s[j + 1];
    int last = -1, kc = 0;
    for (int r = r0; r < r1; ++r) {
      int bi = besti_s[r];
      bool merge = (last > 0) && (bi - last < MIN_GAP);
      int fi = bi;
      if (merge) { int sm2 = bi + last; fi = (sm2 + ((sm2 >> 1) & 1)) >> 1; }  // half-to-even
      if (merge) besti_s[r0 + kc - 1] = fi;
      else       besti_s[r0 + kc++]   = fi;
      last = fi;
    }
    kofs_s[j] = kc;
  }
  __syncthreads();

  int K = block_scan_excl(kofs_s, NC, tid, lane, wv, wsums);
  __syncthreads();
  for (int j = tid; j < NC; j += 256) {
    int off = kofs_s[j];
    int cnt = ((j + 1 < NC) ? kofs_s[j + 1] : K) - off;
    int src = cstart_s[j];
    for (int k = 0; k < cnt; ++k) starts_s[off + k] = besti_s[src + k];
  }
  __syncthreads();

  int lens = lens_s;
  for (int i = tid; i < K; i += 256) {
    int e = starts_s[i];
    ends_s[i] = (e != 0 && e < lens - 1) ? 1 : 0;
  }
  __syncthreads();
  int keep = block_scan_excl(ends_s, K, tid, lane, wv, wsums);

  float* obd = out_bd + (size_t)b * T;
  for (int t = tid; t < T; t += 256) obd[t] = 0.f;
  __syncthreads();
  int* ss = seg_start + b * (T + 2);
  for (int i = tid; i < K; i += 256) {
    int e = starts_s[i];
    if (e != 0 && e < lens - 1) {
      int pos = ends_s[i];
      ss[pos + 1] = e;
      obd[e] = 1.f;
    }
  }
  if (tid == 0) {
    ss[0] = 0;
    ss[keep + 1] = T;
    note_len[b] = keep + 1;
    out_len[b] = (float)(keep + 1);
  }
}

// ---------------- Kernel 3: constant tail logits (zero-agg positions) --------
__global__ __launch_bounds__(256) void k_consts(
    const float* __restrict__ conv_b, const float* __restrict__ ln_g,
    const float* __restrict__ ln_b, const float* __restrict__ post_w,
    const float* __restrict__ post_b, const float* __restrict__ w_pitch,
    const float* __restrict__ b_pitch,
    float* __restrict__ lmid, float* __restrict__ ledge, int* __restrict__ preds)
{
  __shared__ float hc[H], zm[H], ze[H], red[8];
  __shared__ float lm[NOTE_CLS], le[NOTE_CLS];
  int tid = threadIdx.x, lane = tid & 63, wv = tid >> 6;
  float y = conv_b[tid];
  float s = y;
  for (int off = 32; off; off >>= 1) s += __shfl_down(s, off);
  if (lane == 0) red[wv] = s;
  __syncthreads();
  float mean = (red[0] + red[1] + red[2] + red[3]) * (1.0f / H);
  float d = y - mean, q = d * d;
  for (int off = 32; off; off >>= 1) q += __shfl_down(q, off);
  if (lane == 0) red[4 + wv] = q;
  __syncthreads();
  float var = (red[4] + red[5] + red[6] + red[7]) * (1.0f / H);
  float h = d / sqrtf(var + 1e-5f) * ln_g[tid] + ln_b[tid];
  h = h > 0.f ? h : 0.01f * h;
  hc[tid] = h;
  __syncthreads();
  float am = 0.f, ae = 0.f;
  for (int cin = 0; cin < H; ++cin) {
    float hv = hc[cin];
    float p0 = post_w[(0 * H + cin) * H + tid];
    float p1 = post_w[(1 * H + cin) * H + tid];
    float p2 = post_w[(2 * H + cin) * H + tid];
    am += (p0 + p1 + p2) * hv;
    ae += (p0 + p1) * hv;
  }
  zm[tid] = am + post_b[tid];
  ze[tid] = ae + post_b[tid];
  __syncthreads();
  if (tid < NOTE_CLS) {
    float sm = 0.f, se = 0.f;
    for (int c = 0; c < H; ++c) {
      float w = w_pitch[c * NOTE_CLS + tid];
      sm += zm[c] * w; se += ze[c] * w;
    }
    lm[tid] = sm + b_pitch[tid]; le[tid] = se + b_pitch[tid];
    lmid[tid] = lm[tid]; ledge[tid] = le[tid];
  }
  __syncthreads();
  if (tid == 0) {
    int bi = 0; float bv = lm[0];
    for (int p = 1; p < NOTE_CLS; ++p) if (lm[p] > bv) { bv = lm[p]; bi = p; }
    preds[0] = (bi > NOTE_NUM || bi < NOTE_START) ? 0 : bi;
    bi = 0; bv = le[0];
    for (int p = 1; p < NOTE_CLS; ++p) if (le[p] > bv) { bv = le[p]; bi = p; }
    preds[1] = (bi > NOTE_NUM || bi < NOTE_START) ? 0 : bi;
  }
}

// ---------------- Kernel 4: segment weighted means ---------------------------
__global__ __launch_bounds__(64) void k_seg(
    const float* __restrict__ feat, const float* __restrict__ amean,
    const int* __restrict__ seg_start, const int* __restrict__ note_len,
    float* __restrict__ agg)
{
  int blk = blockIdx.x;
  int b = blk / SEGC, n = blk - b * SEGC;
  int len = note_len[b];
  int lane = threadIdx.x;
  float4* o4 = (float4*)(agg + ((size_t)b * SEGC + n) * H);
  if (n >= len) {
    if (n < len + 40) o4[lane] = make_float4(0.f, 0.f, 0.f, 0.f);
    return;
  }
  int s = seg_start[b * (T + 2) + n];
  int e = seg_start[b * (T + 2) + n + 1];
  float4 acc = make_float4(0.f, 0.f, 0.f, 0.f);
  float dsum = 0.f;
  for (int t = s; t < e; ++t) {
    float am = amean[(size_t)b * T + t];
    float4 f = ((const float4*)(feat + ((size_t)b * T + t) * H))[lane];
    acc.x += am * f.x; acc.y += am * f.y; acc.z += am * f.z; acc.w += am * f.w;
    dsum += am;
  }
  float dn = dsum + 1e-5f;
  acc.x /= dn; acc.y /= dn; acc.z /= dn; acc.w /= dn;
  o4[lane] = acc;
}

// ---- helper: per-batch active ranges ----------------------------------------
__device__ __forceinline__ void conv_ranges(int len, int& Nz, int& MY)
{
  int t16 = ((len + 2) / 16) * 16;
  if (t16 > SEGC - 16) t16 = SEGC - 16;
  Nz = t16 + 16;
  MY = Nz + 2;
  if (MY > NPOS) MY = NPOS;
  if (MY > SEGC) MY = SEGC;
}

// ---------------- Kernel 5a: conv1 + LN + leaky + residual -> u --------------
// grid = B * NCT (tiles of 4 positions), 256 threads = couts.
// 3 scalar coalesced weight loads per cin; unroll 8.
__global__ __launch_bounds__(256) void k_conv1u(
    const float* __restrict__ agg,
    const float* __restrict__ conv_w, const float* __restrict__ conv_b,
    const float* __restrict__ ln_g, const float* __restrict__ ln_b,
    const int* __restrict__ note_len,
    float* __restrict__ u_buf)
{
  int blk = blockIdx.x;
  int b = blk / NCT, tile = blk - b * NCT;
  int t0 = tile * CT;
  int len = note_len[b];
  int Nz, MY;
  conv_ranges(len, Nz, MY);
  if (t0 >= MY) return;

  __shared__ float xs[H][8];                     // agg rows m = t0-1 .. t0+4 (6 used)
  __shared__ float rs_[CT][4], rq_[CT][4];
  __shared__ float smean[CT], srstd[CT];

  int tid = threadIdx.x;
  int lane = tid & 63, wv = tid >> 6;
  const float* aggb = agg + (size_t)b * SEGC * H;

  #pragma unroll
  for (int r = 0; r < 6; ++r) {
    int p = t0 - 1 + r;
    float v = 0.f;
    if (p >= 0 && p < SEGC) v = aggb[(size_t)p * H + tid];
    xs[tid][r] = v;
  }
  xs[tid][6] = 0.f; xs[tid][7] = 0.f;
  __syncthreads();

  float acc[CT];
  #pragma unroll
  for (int j = 0; j < CT; ++j) acc[j] = 0.f;
  #pragma unroll 8
  for (int cin = 0; cin < H; ++cin) {
    float w0 = conv_w[cin * H + tid];
    float w1 = conv_w[(H + cin) * H + tid];
    float w2 = conv_w[(2 * H + cin) * H + tid];
    float4 X = *(const float4*)&xs[cin][0];
    float2 Y = *(const float2*)&xs[cin][4];
    float L[6] = { X.x, X.y, X.z, X.w, Y.x, Y.y };
    #pragma unroll
    for (int j = 0; j < CT; ++j)
      acc[j] += w0 * L[j] + w1 * L[j + 1] + w2 * L[j + 2];
  }
  {
    float cb = conv_b[tid];
    #pragma unroll
    for (int j = 0; j < CT; ++j) acc[j] += cb;
  }

  // LN stats per position
  #pragma unroll 1
  for (int j = 0; j < CT; ++j) {
    float s = acc[j], q = acc[j] * acc[j];
    for (int off = 32; off; off >>= 1) { s += __shfl_down(s, off); q += __shfl_down(q, off); }
    if (lane == 0) { rs_[j][wv] = s; rq_[j][wv] = q; }
  }
  __syncthreads();
  if (tid < CT) {
    float S = rs_[tid][0] + rs_[tid][1] + rs_[tid][2] + rs_[tid][3];
    float Q = rq_[tid][0] + rq_[tid][1] + rq_[tid][2] + rq_[tid][3];
    float mean = S * (1.0f / H);
    float var = Q * (1.0f / H) - mean * mean;
    if (var < 0.f) var = 0.f;
    smean[tid] = mean;
    srstd[tid] = 1.0f / sqrtf(var + 1e-5f);
  }
  __syncthreads();

  float g = ln_g[tid], bb = ln_b[tid];
  float* ub = u_buf + (size_t)b * SEGC * H;
  #pragma unroll
  for (int j = 0; j < CT; ++j) {
    int m = t0 + j;
    if (m < MY) {
      float h = (acc[j] - smean[j]) * srstd[j] * g + bb;
      h = h > 0.f ? h : 0.01f * h;
      ub[(size_t)m * H + tid] = xs[tid][j + 1] + h;   // agg[m] + leaky(LN(y))
    }
  }
}

// ---------------- Kernel 5b: conv2 -> pitch head -> argmax -------------------
// grid = B * NCT (tiles of 4), 256 threads = couts. Covers 4-tiles whose
// enclosing 16-tile satisfies t016 <= len+2 (exact complement of k_tail).
// Pitch head widened: 208 threads = 4 positions x 52 class-pairs (float2).
__global__ __launch_bounds__(256) void k_conv2p(
    const float* __restrict__ u_buf,
    const float* __restrict__ post_w, const float* __restrict__ post_b,
    const float* __restrict__ w_pitch, const float* __restrict__ b_pitch,
    const int* __restrict__ note_len,
    float* __restrict__ out3, float* __restrict__ out4)
{
  int blk = blockIdx.x;
  int b = blk / NCT, tile = blk - b * NCT;
  int t0 = tile * CT;
  int len = note_len[b];
  if ((t0 & ~15) > len + 2) return;              // k_tail covers the rest
  int Nz, MY;
  conv_ranges(len, Nz, MY);

  __shared__ float us_[H][8];                    // u rows m = t0-1 .. t0+4 (6 used)
  __shared__ float zt[CT * ZSTR];                // z transposed [n][cout]
  __shared__ float pvs[CT][52];
  __shared__ int   pis[CT][52];

  int tid = threadIdx.x;
  const float* ub = u_buf + (size_t)b * SEGC * H;

  #pragma unroll
  for (int r = 0; r < 6; ++r) {
    int m = t0 - 1 + r;
    float v = 0.f;
    if (m >= 0 && m < MY) v = ub[(size_t)m * H + tid];
    us_[tid][r] = v;
  }
  us_[tid][6] = 0.f; us_[tid][7] = 0.f;
  __syncthreads();

  float acc[CT];
  #pragma unroll
  for (int j = 0; j < CT; ++j) acc[j] = 0.f;
  #pragma unroll 8
  for (int cin = 0; cin < H; ++cin) {
    float w0 = post_w[cin * H + tid];
    float w1 = post_w[(H + cin) * H + tid];
    float w2 = post_w[(2 * H + cin) * H + tid];
    float4 X = *(const float4*)&us_[cin][0];
    float2 Y = *(const float2*)&us_[cin][4];
    float L[6] = { X.x, X.y, X.z, X.w, Y.x, Y.y };
    #pragma unroll
    for (int j = 0; j < CT; ++j)
      acc[j] += w0 * L[j] + w1 * L[j + 1] + w2 * L[j + 2];
  }
  {
    float pb = post_b[tid];
    #pragma unroll
    for (int j = 0; j < CT; ++j) zt[j * ZSTR + tid] = acc[j] + pb;
  }
  __syncthreads();

  // pitch head: 208 threads = 4 positions x 52 class-pairs (float2 loads)
  if (tid < 208) {
    int n4 = tid / 52, c52 = tid - n4 * 52;
    float ax = 0.f, ay = 0.f;
    const float* z = &zt[n4 * ZSTR];
    #pragma unroll 8
    for (int cin = 0; cin < H; ++cin) {
      float2 w2 = *(const float2*)&w_pitch[cin * NOTE_CLS + 2 * c52];
      float zv = z[cin];
      ax += zv * w2.x; ay += zv * w2.y;
    }
    float2 bp = *(const float2*)&b_pitch[2 * c52];
    ax += bp.x; ay += bp.y;
    int n = t0 + n4;
    if (n < NPOS) {
      float2 o; o.x = ax; o.y = ay;
      *(float2*)&out3[((size_t)b * NPOS + n) * NOTE_CLS + 2 * c52] = o;
    }
    float bv = ax; int bi = 2 * c52;
    if (ay > bv) { bv = ay; bi = 2 * c52 + 1; }
    pvs[n4][c52] = bv; pis[n4][c52] = bi;
  }
  __syncthreads();
  if (tid < CT && t0 + tid < NPOS) {
    float bv = pvs[tid][0]; int bi = pis[tid][0];
    #pragma unroll 1
    for (int k = 1; k < 52; ++k)
      if (pvs[tid][k] > bv) { bv = pvs[tid][k]; bi = pis[tid][k]; }
    int pred = (bi > NOTE_NUM || bi < NOTE_START) ? 0 : bi;
    out4[(size_t)b * NPOS + t0 + tid] = (float)pred;
  }
}

// ---------------- Kernel 6: constant tail broadcast (16-tiles) ---------------
__global__ __launch_bounds__(256) void k_tail(
    const float* __restrict__ lmid, const float* __restrict__ ledge,
    const int* __restrict__ preds, const int* __restrict__ note_len,
    float* __restrict__ out3, float* __restrict__ out4)
{
  int blk = blockIdx.x;
  int b = blk / NT2, tile = blk - b * NT2;
  int t0 = tile * T2;
  int len = note_len[b];
  if (t0 <= len + 2) return;                    // handled by conv path
  __shared__ float lm[NOTE_CLS], le[NOTE_CLS];
  int tid = threadIdx.x;
  if (tid < NOTE_CLS) { lm[tid] = lmid[tid]; le[tid] = ledge[tid]; }
  __syncthreads();
  int pm = preds[0], pe = preds[1];
  for (int i = tid; i < T2 * NOTE_CLS; i += 256) {
    int dn = i / NOTE_CLS;
    int n = t0 + dn, p = i - dn * NOTE_CLS;
    if (n >= NPOS) continue;
    out3[((size_t)b * NPOS + n) * NOTE_CLS + p] = (n == NPOS - 1) ? le[p] : lm[p];
  }
  if (tid < T2) {
    int n = t0 + tid;
    if (n < NPOS) out4[(size_t)b * NPOS + n] = (float)((n == NPOS - 1) ? pe : pm);
  }
}

// ---------------- launcher ---------------------------------------------------
extern "C" void kernel_launch(void* const* d_in, const int* in_sizes, int n_in,
                              void* d_out, int out_size, void* d_ws, size_t ws_size,
                              hipStream_t stream) {
  (void)in_sizes; (void)n_in; (void)out_size; (void)ws_size;
  const float* feat    = (const float*)d_in[0];
  const int*   nonpad  = (const int*)d_in[1];
  const float* w_bd    = (const float*)d_in[2];
  const float* b_bd    = (const float*)d_in[3];
  const float* w_attn  = (const float*)d_in[4];
  const float* b_attn  = (const float*)d_in[5];
  const float* conv_w  = (const float*)d_in[6];
  const float* conv_b  = (const float*)d_in[7];
  const float* ln_g    = (const float*)d_in[8];
  const float* ln_b    = (const float*)d_in[9];
  const float* post_w  = (const float*)d_in[10];
  const float* post_b  = (const float*)d_in[11];
  const float* w_pitch = (const float*)d_in[12];
  const float* b_pitch = (const float*)d_in[13];

  float* out  = (float*)d_out;
  float* out0 = out;                                  // [B,T] note_bd_logits
  float* out1 = out + (size_t)B * T;                  // [B,T] note_bd
  float* out2 = out + 2ull * B * T;                   // [B]   note_lengths
  float* out3 = out2 + B;                             // [B,NPOS,104] note_logits
  float* out4 = out3 + (size_t)B * NPOS * NOTE_CLS;   // [B,NPOS] note_pred

  char* ws = (char*)d_ws;
  double* dlog  = (double*)(ws + 0);                  // 768000 B
  float*  amean = (float*)(ws + 768000);              // 384000 B
  int*    segst = (int*)(ws + 1152000);               // 384128 B
  int*    nlen  = (int*)(ws + 1536128);               // 64 B
  float*  lmid  = (float*)(ws + 1536192);             // 416 B
  float*  ledge = (float*)(ws + 1536608);             // 416 B
  int*    preds = (int*)(ws + 1537024);               // 512 B
  float*  agg   = (float*)(ws + 1537536);             // 16*384*256*4 = 6291456 B
  float*  u_buf = (float*)(ws + 1537536 + 6291456);   // 6291456 B (total ~14.1 MB)

  k_dots<<<(B * T) / 4, 256, 0, stream>>>(feat, w_bd, b_bd, w_attn, b_attn, out0, dlog, amean);
  k_regulate<<<B, 256, 0, stream>>>(dlog, nonpad, out1, out2, segst, nlen);
  k_consts<<<1, 256, 0, stream>>>(conv_b, ln_g, ln_b, post_w, post_b, w_pitch, b_pitch, lmid, ledge, preds);
  k_seg<<<B * SEGC, 64, 0, stream>>>(feat, amean, segst, nlen, agg);
  k_conv1u<<<B * NCT, 256, 0, stream>>>(agg, conv_w, conv_b, ln_g, ln_b, nlen, u_buf);
  k_conv2p<<<B * NCT, 256, 0, stream>>>(u_buf, post_w, post_b, w_pitch, b_pitch, nlen, out3, out4);
  k_tail<<<B * NT2, 256, 0, stream>>>(lmid, ledge, preds, nlen, out3, out4);
}

// Round 17
// 281.491 us; speedup vs baseline: 1.0593x; 1.0593x over previous
//
#include <hip/hip_runtime.h>
#include <math.h>

#define B 16
#define T 6000
#define H 256
#define NPOS 6001            // T+1 segments
#define NOTE_CLS 104
#define NOTE_NUM 100
#define NOTE_START 30
#define MIN_GAP 9
#define SEGC 384             // materialized agg/u rows per batch (len ~255 + headroom)

#define T2 16                // k_tail tile (positions)
#define NT2 ((NPOS + T2 - 1) / T2)      // 376
#define CT 4                 // conv tile (positions per block)
#define NCT (SEGC / CT)      // 96
#define ZSTR 260

#define NWORDS 94            // ceil(T/64)
#define MAXRUNS 3088

// ---------------- Kernel 1: bd + attn dot products (f64 accumulate) ----------
__global__ __launch_bounds__(256) void k_dots(
    const float* __restrict__ feat,
    const float* __restrict__ w_bd, const float* __restrict__ b_bd,
    const float* __restrict__ w_attn, const float* __restrict__ b_attn,
    float* __restrict__ out_logits, double* __restrict__ dlog,
    float* __restrict__ amean)
{
  int lane = threadIdx.x & 63, wv = threadIdx.x >> 6;
  int row = blockIdx.x * 4 + wv;                      // b*T + t
  if (row >= B * T) return;
  float4 f  = ((const float4*)(feat + (size_t)row * H))[lane];
  float4 wb = ((const float4*)w_bd)[lane];
  float4 wa = ((const float4*)w_attn)[lane];
  double sb = (double)f.x * wb.x + (double)f.y * wb.y + (double)f.z * wb.z + (double)f.w * wb.w;
  double sa = (double)f.x * wa.x + (double)f.y * wa.y + (double)f.z * wa.z + (double)f.w * wa.w;
  for (int off = 32; off; off >>= 1) { sb += __shfl_down(sb, off); sa += __shfl_down(sa, off); }
  if (lane == 0) {
    double lb = sb + (double)b_bd[0];
    lb = fmin(fmax(lb, -16.0), 16.0);
    out_logits[row] = (float)lb;
    dlog[row] = lb;
    double la = sa + (double)b_attn[0];
    amean[row] = (float)(1.0 / (1.0 + exp(-la)));
  }
}

// ---------------- block-wide exclusive scan helper (in-place), n uniform -----
__device__ __forceinline__ int block_scan_excl(int* a, int n, int tid, int lane,
                                               int wv, int* wsums)
{
  int base = 0;
  for (int c0 = 0; c0 < n; c0 += 256) {
    int i = c0 + tid;
    int v = (i < n) ? a[i] : 0;
    int s = v;
    #pragma unroll
    for (int off = 1; off < 64; off <<= 1) {
      int t = __shfl_up(s, off);
      if (lane >= off) s += t;
    }
    if (lane == 63) wsums[wv] = s;
    __syncthreads();
    int wbase = 0;
    for (int w = 0; w < wv; ++w) wbase += wsums[w];
    int ctot = wsums[0] + wsums[1] + wsums[2] + wsums[3];
    if (i < n) a[i] = base + wbase + s - v;    // exclusive
    base += ctot;
    __syncthreads();
  }
  return base;
}

// ---------------- Kernel 2: regulate_boundary (cluster-parallel chain) -------
__global__ __launch_bounds__(256) void k_regulate(
    const double* __restrict__ dlog, const int* __restrict__ non_padding,
    float* __restrict__ out_bd, float* __restrict__ out_len,
    int* __restrict__ seg_start, int* __restrict__ note_len)
{
  __shared__ double row_s[T];                    // 48000 B
  __shared__ unsigned long long words[96];
  __shared__ unsigned long long smask[NWORDS], emask[NWORDS];
  __shared__ int wcnt[NWORDS], woff[NWORDS], ecnt[NWORDS], eoff[NWORDS];
  __shared__ int starts_s[MAXRUNS];
  __shared__ int ends_s[MAXRUNS];
  __shared__ int besti_s[MAXRUNS];
  __shared__ int cstart_s[MAXRUNS + 1];
  __shared__ int kofs_s[MAXRUNS];
  __shared__ unsigned long long cmask[52];
  __shared__ int ccnt[52], coff[52];
  __shared__ int wsums[4], red_i[4];
  __shared__ int R_s, NC_s, lens_s;

  int b = blockIdx.x, tid = threadIdx.x;
  int lane = tid & 63, wv = tid >> 6;
  const double* row = dlog + (size_t)b * T;

  // --- Phase A: stage row in LDS + bit words ---
  for (int c = 0; c < 24; ++c) {
    int t = c * 256 + tid;
    double d = (t < T) ? row[t] : -1.0;
    if (t < T) row_s[t] = d;
    unsigned long long m = __ballot((t < T) && (d > 0.0));
    if (lane == 0) words[c * 4 + wv] = m;
  }
  __syncthreads();

  if (tid < NWORDS) {
    unsigned long long bits = words[tid];
    unsigned long long carry = (tid > 0) ? (words[tid - 1] >> 63) : 0ull;
    unsigned long long pm = (bits << 1) | carry;
    unsigned long long sm = bits & ~pm;
    unsigned long long em = (~bits) & pm;
    smask[tid] = sm;  emask[tid] = em;
    wcnt[tid] = __popcll(sm);  ecnt[tid] = __popcll(em);
  }
  __syncthreads();

  if (tid == 0) {
    int a = 0, e = 0;
    #pragma unroll 8
    for (int w = 0; w < NWORDS; ++w) {
      woff[w] = a; a += wcnt[w];
      eoff[w] = e; e += ecnt[w];
    }
    R_s = a;
  }
  __syncthreads();

  if (tid < NWORDS) {
    unsigned long long m = smask[tid];
    int off = woff[tid], base = tid * 64;
    while (m) { int i = __builtin_ctzll(m); starts_s[off++] = base + i; m &= m - 1; }
    m = emask[tid]; off = eoff[tid];
    while (m) { int i = __builtin_ctzll(m); ends_s[off++] = base + i; m &= m - 1; }
  }

  {
    int lens = 0;
    const int* npr = non_padding + (size_t)b * T;
    for (int t = tid; t < T; t += 256) lens += npr[t];
    for (int off = 32; off; off >>= 1) lens += __shfl_down(lens, off);
    if (lane == 0) red_i[wv] = lens;
  }
  __syncthreads();
  if (tid == 0) lens_s = red_i[0] + red_i[1] + red_i[2] + red_i[3];

  int R = R_s;
  int bd_last = (int)((words[(T - 1) >> 6] >> ((T - 1) & 63)) & 1ull);
  int Rc = R - (bd_last ? 1 : 0);          // trailing unclosed run excluded

  // --- Phase B: per-run argmax (break-free, LDS reads) ---
  for (int r = tid; r < R; r += 256) {
    int s = starts_s[r];
    int e = (r < Rc) ? ends_s[r] : T;
    double bv = row_s[s];
    int bi = s;
    for (int t = s + 1; t < e; ++t) {
      double d = row_s[t];
      if (d > bv) { bv = d; bi = t; }
    }
    besti_s[r] = bi;
  }
  __syncthreads();

  // --- cluster boundaries ---
  int NRW = (Rc + 63) >> 6;
  for (int c0 = 0; c0 < NRW * 64; c0 += 256) {
    int r = c0 + tid;
    bool fl = false;
    if (r < Rc) fl = (r == 0) || (besti_s[r] - besti_s[r - 1] >= MIN_GAP);
    unsigned long long m = __ballot(fl);
    int widx = (c0 >> 6) + wv;
    if (lane == 0 && widx < 52) cmask[widx] = m;
  }
  __syncthreads();
  if (tid < NRW) ccnt[tid] = __popcll(cmask[tid]);
  __syncthreads();
  if (tid == 0) {
    int a = 0;
    for (int w = 0; w < NRW; ++w) { coff[w] = a; a += ccnt[w]; }
    NC_s = a;
  }
  __syncthreads();
  if (tid < NRW) {
    unsigned long long m = cmask[tid];
    int off = coff[tid], base = tid * 64;
    while (m) { int i = __builtin_ctzll(m); cstart_s[off++] = base + i; m &= m - 1; }
  }
  __syncthreads();
  int NC = NC_s;
  if (tid == 0) cstart_s[NC] = Rc;
  __syncthreads();

  // --- Phase C: per-cluster merge chains ---
  for (int j = tid; j < NC; j += 256) {
    int r0 = cstart_s[j], r1 = cstart_s[j + 1];
    int last = -1, kc = 0;
    for (int r = r0; r < r1; ++r) {
      int bi = besti_s[r];
      bool merge = (last > 0) && (bi - last < MIN_GAP);
      int fi = bi;
      if (merge) { int sm2 = bi + last; fi = (sm2 + ((sm2 >> 1) & 1)) >> 1; }  // half-to-even
      if (merge) besti_s[r0 + kc - 1] = fi;
      else       besti_s[r0 + kc++]   = fi;
      last = fi;
    }
    kofs_s[j] = kc;
  }
  __syncthreads();

  int K = block_scan_excl(kofs_s, NC, tid, lane, wv, wsums);
  __syncthreads();
  for (int j = tid; j < NC; j += 256) {
    int off = kofs_s[j];
    int cnt = ((j + 1 < NC) ? kofs_s[j + 1] : K) - off;
    int src = cstart_s[j];
    for (int k = 0; k < cnt; ++k) starts_s[off + k] = besti_s[src + k];
  }
  __syncthreads();

  int lens = lens_s;
  for (int i = tid; i < K; i += 256) {
    int e = starts_s[i];
    ends_s[i] = (e != 0 && e < lens - 1) ? 1 : 0;
  }
  __syncthreads();
  int keep = block_scan_excl(ends_s, K, tid, lane, wv, wsums);

  float* obd = out_bd + (size_t)b * T;
  for (int t = tid; t < T; t += 256) obd[t] = 0.f;
  __syncthreads();
  int* ss = seg_start + b * (T + 2);
  for (int i = tid; i < K; i += 256) {
    int e = starts_s[i];
    if (e != 0 && e < lens - 1) {
      int pos = ends_s[i];
      ss[pos + 1] = e;
      obd[e] = 1.f;
    }
  }
  if (tid == 0) {
    ss[0] = 0;
    ss[keep + 1] = T;
    note_len[b] = keep + 1;
    out_len[b] = (float)(keep + 1);
  }
}

// ---------------- Kernel 3: constant tail logits (zero-agg positions) --------
__global__ __launch_bounds__(256) void k_consts(
    const float* __restrict__ conv_b, const float* __restrict__ ln_g,
    const float* __restrict__ ln_b, const float* __restrict__ post_w,
    const float* __restrict__ post_b, const float* __restrict__ w_pitch,
    const float* __restrict__ b_pitch,
    float* __restrict__ lmid, float* __restrict__ ledge, int* __restrict__ preds)
{
  __shared__ float hc[H], zm[H], ze[H], red[8];
  __shared__ float lm[NOTE_CLS], le[NOTE_CLS];
  int tid = threadIdx.x, lane = tid & 63, wv = tid >> 6;
  float y = conv_b[tid];
  float s = y;
  for (int off = 32; off; off >>= 1) s += __shfl_down(s, off);
  if (lane == 0) red[wv] = s;
  __syncthreads();
  float mean = (red[0] + red[1] + red[2] + red[3]) * (1.0f / H);
  float d = y - mean, q = d * d;
  for (int off = 32; off; off >>= 1) q += __shfl_down(q, off);
  if (lane == 0) red[4 + wv] = q;
  __syncthreads();
  float var = (red[4] + red[5] + red[6] + red[7]) * (1.0f / H);
  float h = d / sqrtf(var + 1e-5f) * ln_g[tid] + ln_b[tid];
  h = h > 0.f ? h : 0.01f * h;
  hc[tid] = h;
  __syncthreads();
  float am = 0.f, ae = 0.f;
  for (int cin = 0; cin < H; ++cin) {
    float hv = hc[cin];
    float p0 = post_w[(0 * H + cin) * H + tid];
    float p1 = post_w[(1 * H + cin) * H + tid];
    float p2 = post_w[(2 * H + cin) * H + tid];
    am += (p0 + p1 + p2) * hv;
    ae += (p0 + p1) * hv;
  }
  zm[tid] = am + post_b[tid];
  ze[tid] = ae + post_b[tid];
  __syncthreads();
  if (tid < NOTE_CLS) {
    float sm = 0.f, se = 0.f;
    for (int c = 0; c < H; ++c) {
      float w = w_pitch[c * NOTE_CLS + tid];
      sm += zm[c] * w; se += ze[c] * w;
    }
    lm[tid] = sm + b_pitch[tid]; le[tid] = se + b_pitch[tid];
    lmid[tid] = lm[tid]; ledge[tid] = le[tid];
  }
  __syncthreads();
  if (tid == 0) {
    int bi = 0; float bv = lm[0];
    for (int p = 1; p < NOTE_CLS; ++p) if (lm[p] > bv) { bv = lm[p]; bi = p; }
    preds[0] = (bi > NOTE_NUM || bi < NOTE_START) ? 0 : bi;
    bi = 0; bv = le[0];
    for (int p = 1; p < NOTE_CLS; ++p) if (le[p] > bv) { bv = le[p]; bi = p; }
    preds[1] = (bi > NOTE_NUM || bi < NOTE_START) ? 0 : bi;
  }
}

// ---------------- Kernel 4: segment weighted means ---------------------------
__global__ __launch_bounds__(64) void k_seg(
    const float* __restrict__ feat, const float* __restrict__ amean,
    const int* __restrict__ seg_start, const int* __restrict__ note_len,
    float* __restrict__ agg)
{
  int blk = blockIdx.x;
  int b = blk / SEGC, n = blk - b * SEGC;
  int len = note_len[b];
  int lane = threadIdx.x;
  float4* o4 = (float4*)(agg + ((size_t)b * SEGC + n) * H);
  if (n >= len) {
    if (n < len + 40) o4[lane] = make_float4(0.f, 0.f, 0.f, 0.f);
    return;
  }
  int s = seg_start[b * (T + 2) + n];
  int e = seg_start[b * (T + 2) + n + 1];
  float4 acc = make_float4(0.f, 0.f, 0.f, 0.f);
  float dsum = 0.f;
  for (int t = s; t < e; ++t) {
    float am = amean[(size_t)b * T + t];
    float4 f = ((const float4*)(feat + ((size_t)b * T + t) * H))[lane];
    acc.x += am * f.x; acc.y += am * f.y; acc.z += am * f.z; acc.w += am * f.w;
    dsum += am;
  }
  float dn = dsum + 1e-5f;
  acc.x /= dn; acc.y /= dn; acc.z /= dn; acc.w /= dn;
  o4[lane] = acc;
}

// ---- helper: per-batch active ranges ----------------------------------------
__device__ __forceinline__ void conv_ranges(int len, int& Nz, int& MY)
{
  int t16 = ((len + 2) / 16) * 16;
  if (t16 > SEGC - 16) t16 = SEGC - 16;
  Nz = t16 + 16;
  MY = Nz + 2;
  if (MY > NPOS) MY = NPOS;
  if (MY > SEGC) MY = SEGC;
}

// ---------------- Kernel 5a: conv1 + LN + leaky + residual -> u --------------
// grid = B * NCT (tiles of 4 positions), 256 threads = couts.
// 3 scalar coalesced weight loads per cin; unroll 8.
__global__ __launch_bounds__(256) void k_conv1u(
    const float* __restrict__ agg,
    const float* __restrict__ conv_w, const float* __restrict__ conv_b,
    const float* __restrict__ ln_g, const float* __restrict__ ln_b,
    const int* __restrict__ note_len,
    float* __restrict__ u_buf)
{
  int blk = blockIdx.x;
  int b = blk / NCT, tile = blk - b * NCT;
  int t0 = tile * CT;
  int len = note_len[b];
  int Nz, MY;
  conv_ranges(len, Nz, MY);
  if (t0 >= MY) return;

  __shared__ float xs[H][8];                     // agg rows m = t0-1 .. t0+4 (6 used)
  __shared__ float rs_[CT][4], rq_[CT][4];
  __shared__ float smean[CT], srstd[CT];

  int tid = threadIdx.x;
  int lane = tid & 63, wv = tid >> 6;
  const float* aggb = agg + (size_t)b * SEGC * H;

  #pragma unroll
  for (int r = 0; r < 6; ++r) {
    int p = t0 - 1 + r;
    float v = 0.f;
    if (p >= 0 && p < SEGC) v = aggb[(size_t)p * H + tid];
    xs[tid][r] = v;
  }
  xs[tid][6] = 0.f; xs[tid][7] = 0.f;
  __syncthreads();

  float acc[CT];
  #pragma unroll
  for (int j = 0; j < CT; ++j) acc[j] = 0.f;
  #pragma unroll 8
  for (int cin = 0; cin < H; ++cin) {
    float w0 = conv_w[cin * H + tid];
    float w1 = conv_w[(H + cin) * H + tid];
    float w2 = conv_w[(2 * H + cin) * H + tid];
    float4 X = *(const float4*)&xs[cin][0];
    float2 Y = *(const float2*)&xs[cin][4];
    float L[6] = { X.x, X.y, X.z, X.w, Y.x, Y.y };
    #pragma unroll
    for (int j = 0; j < CT; ++j)
      acc[j] += w0 * L[j] + w1 * L[j + 1] + w2 * L[j + 2];
  }
  {
    float cb = conv_b[tid];
    #pragma unroll
    for (int j = 0; j < CT; ++j) acc[j] += cb;
  }

  // LN stats per position
  #pragma unroll 1
  for (int j = 0; j < CT; ++j) {
    float s = acc[j], q = acc[j] * acc[j];
    for (int off = 32; off; off >>= 1) { s += __shfl_down(s, off); q += __shfl_down(q, off); }
    if (lane == 0) { rs_[j][wv] = s; rq_[j][wv] = q; }
  }
  __syncthreads();
  if (tid < CT) {
    float S = rs_[tid][0] + rs_[tid][1] + rs_[tid][2] + rs_[tid][3];
    float Q = rq_[tid][0] + rq_[tid][1] + rq_[tid][2] + rq_[tid][3];
    float mean = S * (1.0f / H);
    float var = Q * (1.0f / H) - mean * mean;
    if (var < 0.f) var = 0.f;
    smean[tid] = mean;
    srstd[tid] = 1.0f / sqrtf(var + 1e-5f);
  }
  __syncthreads();

  float g = ln_g[tid], bb = ln_b[tid];
  float* ub = u_buf + (size_t)b * SEGC * H;
  #pragma unroll
  for (int j = 0; j < CT; ++j) {
    int m = t0 + j;
    if (m < MY) {
      float h = (acc[j] - smean[j]) * srstd[j] * g + bb;
      h = h > 0.f ? h : 0.01f * h;
      ub[(size_t)m * H + tid] = xs[tid][j + 1] + h;   // agg[m] + leaky(LN(y))
    }
  }
}

// ---------------- Kernel 5b: conv2 -> pitch head -> argmax -------------------
// grid = B * NCT (tiles of 4), 256 threads = couts. Covers 4-tiles whose
// enclosing 16-tile satisfies t016 <= len+2 (exact complement of k_tail).
__global__ __launch_bounds__(256) void k_conv2p(
    const float* __restrict__ u_buf,
    const float* __restrict__ post_w, const float* __restrict__ post_b,
    const float* __restrict__ w_pitch, const float* __restrict__ b_pitch,
    const int* __restrict__ note_len,
    float* __restrict__ out3, float* __restrict__ out4)
{
  int blk = blockIdx.x;
  int b = blk / NCT, tile = blk - b * NCT;
  int t0 = tile * CT;
  int len = note_len[b];
  if ((t0 & ~15) > len + 2) return;              // k_tail covers the rest
  int Nz, MY;
  conv_ranges(len, Nz, MY);

  __shared__ float us_[H][8];                    // u rows m = t0-1 .. t0+4 (6 used)
  __shared__ float zt[CT * ZSTR];                // z transposed [n][cout]
  __shared__ float pvs[CT][26];
  __shared__ int   pis[CT][26];

  int tid = threadIdx.x;
  const float* ub = u_buf + (size_t)b * SEGC * H;

  #pragma unroll
  for (int r = 0; r < 6; ++r) {
    int m = t0 - 1 + r;
    float v = 0.f;
    if (m >= 0 && m < MY) v = ub[(size_t)m * H + tid];
    us_[tid][r] = v;
  }
  us_[tid][6] = 0.f; us_[tid][7] = 0.f;
  __syncthreads();

  float acc[CT];
  #pragma unroll
  for (int j = 0; j < CT; ++j) acc[j] = 0.f;
  #pragma unroll 8
  for (int cin = 0; cin < H; ++cin) {
    float w0 = post_w[cin * H + tid];
    float w1 = post_w[(H + cin) * H + tid];
    float w2 = post_w[(2 * H + cin) * H + tid];
    float4 X = *(const float4*)&us_[cin][0];
    float2 Y = *(const float2*)&us_[cin][4];
    float L[6] = { X.x, X.y, X.z, X.w, Y.x, Y.y };
    #pragma unroll
    for (int j = 0; j < CT; ++j)
      acc[j] += w0 * L[j] + w1 * L[j + 1] + w2 * L[j + 2];
  }
  {
    float pb = post_b[tid];
    #pragma unroll
    for (int j = 0; j < CT; ++j) zt[j * ZSTR + tid] = acc[j] + pb;
  }
  __syncthreads();

  // pitch head: 104 threads = 4 positions x 26 class-quads
  if (tid < 104) {
    int n8 = tid / 26, c26 = tid - n8 * 26;
    float4 a = make_float4(0.f, 0.f, 0.f, 0.f);
    const float* z = &zt[n8 * ZSTR];
    #pragma unroll 8
    for (int cin = 0; cin < H; ++cin) {
      float4 w4 = *(const float4*)&w_pitch[cin * NOTE_CLS + 4 * c26];
      float zv = z[cin];
      a.x += zv * w4.x; a.y += zv * w4.y; a.z += zv * w4.z; a.w += zv * w4.w;
    }
    float4 bp = *(const float4*)&b_pitch[4 * c26];
    a.x += bp.x; a.y += bp.y; a.z += bp.z; a.w += bp.w;
    int n = t0 + n8;
    if (n < NPOS)
      *(float4*)&out3[((size_t)b * NPOS + n) * NOTE_CLS + 4 * c26] = a;
    float bv = a.x; int bi = 4 * c26;
    if (a.y > bv) { bv = a.y; bi = 4 * c26 + 1; }
    if (a.z > bv) { bv = a.z; bi = 4 * c26 + 2; }
    if (a.w > bv) { bv = a.w; bi = 4 * c26 + 3; }
    pvs[n8][c26] = bv; pis[n8][c26] = bi;
  }
  __syncthreads();
  if (tid < CT && t0 + tid < NPOS) {
    float bv = pvs[tid][0]; int bi = pis[tid][0];
    #pragma unroll 1
    for (int k = 1; k < 26; ++k)
      if (pvs[tid][k] > bv) { bv = pvs[tid][k]; bi = pis[tid][k]; }
    int pred = (bi > NOTE_NUM || bi < NOTE_START) ? 0 : bi;
    out4[(size_t)b * NPOS + t0 + tid] = (float)pred;
  }
}

// ---------------- Kernel 6: constant tail broadcast (16-tiles) ---------------
__global__ __launch_bounds__(256) void k_tail(
    const float* __restrict__ lmid, const float* __restrict__ ledge,
    const int* __restrict__ preds, const int* __restrict__ note_len,
    float* __restrict__ out3, float* __restrict__ out4)
{
  int blk = blockIdx.x;
  int b = blk / NT2, tile = blk - b * NT2;
  int t0 = tile * T2;
  int len = note_len[b];
  if (t0 <= len + 2) return;                    // handled by conv path
  __shared__ float lm[NOTE_CLS], le[NOTE_CLS];
  int tid = threadIdx.x;
  if (tid < NOTE_CLS) { lm[tid] = lmid[tid]; le[tid] = ledge[tid]; }
  __syncthreads();
  int pm = preds[0], pe = preds[1];
  for (int i = tid; i < T2 * NOTE_CLS; i += 256) {
    int dn = i / NOTE_CLS;
    int n = t0 + dn, p = i - dn * NOTE_CLS;
    if (n >= NPOS) continue;
    out3[((size_t)b * NPOS + n) * NOTE_CLS + p] = (n == NPOS - 1) ? le[p] : lm[p];
  }
  if (tid < T2) {
    int n = t0 + tid;
    if (n < NPOS) out4[(size_t)b * NPOS + n] = (float)((n == NPOS - 1) ? pe : pm);
  }
}

// ---------------- launcher ---------------------------------------------------
extern "C" void kernel_launch(void* const* d_in, const int* in_sizes, int n_in,
                              void* d_out, int out_size, void* d_ws, size_t ws_size,
                              hipStream_t stream) {
  (void)in_sizes; (void)n_in; (void)out_size; (void)ws_size;
  const float* feat    = (const float*)d_in[0];
  const int*   nonpad  = (const int*)d_in[1];
  const float* w_bd    = (const float*)d_in[2];
  const float* b_bd    = (const float*)d_in[3];
  const float* w_attn  = (const float*)d_in[4];
  const float* b_attn  = (const float*)d_in[5];
  const float* conv_w  = (const float*)d_in[6];
  const float* conv_b  = (const float*)d_in[7];
  const float* ln_g    = (const float*)d_in[8];
  const float* ln_b    = (const float*)d_in[9];
  const float* post_w  = (const float*)d_in[10];
  const float* post_b  = (const float*)d_in[11];
  const float* w_pitch = (const float*)d_in[12];
  const float* b_pitch = (const float*)d_in[13];

  float* out  = (float*)d_out;
  float* out0 = out;                                  // [B,T] note_bd_logits
  float* out1 = out + (size_t)B * T;                  // [B,T] note_bd
  float* out2 = out + 2ull * B * T;                   // [B]   note_lengths
  float* out3 = out2 + B;                             // [B,NPOS,104] note_logits
  float* out4 = out3 + (size_t)B * NPOS * NOTE_CLS;   // [B,NPOS] note_pred

  char* ws = (char*)d_ws;
  double* dlog  = (double*)(ws + 0);                  // 768000 B
  float*  amean = (float*)(ws + 768000);              // 384000 B
  int*    segst = (int*)(ws + 1152000);               // 384128 B
  int*    nlen  = (int*)(ws + 1536128);               // 64 B
  float*  lmid  = (float*)(ws + 1536192);             // 416 B
  float*  ledge = (float*)(ws + 1536608);             // 416 B
  int*    preds = (int*)(ws + 1537024);               // 512 B
  float*  agg   = (float*)(ws + 1537536);             // 16*384*256*4 = 6291456 B
  float*  u_buf = (float*)(ws + 1537536 + 6291456);   // 6291456 B (total ~14.1 MB)

  k_dots<<<(B * T) / 4, 256, 0, stream>>>(feat, w_bd, b_bd, w_attn, b_attn, out0, dlog, amean);
  k_regulate<<<B, 256, 0, stream>>>(dlog, nonpad, out1, out2, segst, nlen);
  k_consts<<<1, 256, 0, stream>>>(conv_b, ln_g, ln_b, post_w, post_b, w_pitch, b_pitch, lmid, ledge, preds);
  k_seg<<<B * SEGC, 64, 0, stream>>>(feat, amean, segst, nlen, agg);
  k_conv1u<<<B * NCT, 256, 0, stream>>>(agg, conv_w, conv_b, ln_g, ln_b, nlen, u_buf);
  k_conv2p<<<B * NCT, 256, 0, stream>>>(u_buf, post_w, post_b, w_pitch, b_pitch, nlen, out3, out4);
  k_tail<<<B * NT2, 256, 0, stream>>>(lmid, ledge, preds, nlen, out3, out4);
}